// Round 2
// baseline (266.427 us; speedup 1.0000x reference)
//
#include <hip/hip_runtime.h>
#include <math.h>

#define SUPPORT 1.5f

// ---------------- hat basis ----------------
__device__ __forceinline__ void hat4(float u, float h[4]) {
    // centers linspace(-1,1,4), spacing 2/3 -> relu(1 - |u-c|*1.5)
#pragma unroll
    for (int j = 0; j < 4; ++j) {
        float c = -1.0f + j * (2.0f / 3.0f);
        h[j] = fmaxf(0.0f, 1.0f - fabsf(u - c) * 1.5f);
    }
}

// ---------------- per-edge RBF coefficients ----------------
// NEG=false: d = clamp((pa[ia] - pb[ib]) / SUPPORT)            (boundary edges)
// NEG=true : d = clamp(-((pa[ia] - pb[ib]) / SUPPORT))         (fluid edges, bit-exact
//            with the reference's -(P[j]-P[i])/S including signed zeros -> atan2 branch)
template <bool NEG>
__global__ void coeff_kernel(const float2* __restrict__ pa, const int* __restrict__ ia,
                             const float2* __restrict__ pb, const int* __restrict__ ib,
                             float* __restrict__ out, int E) {
    int e = blockIdx.x * blockDim.x + threadIdx.x;
    if (e >= E) return;
    float2 A = pa[ia[e]];
    float2 B = pb[ib[e]];
    float rx = (A.x - B.x) / SUPPORT;
    float ry = (A.y - B.y) / SUPPORT;
    if (NEG) { rx = -rx; ry = -ry; }
    float dx = fminf(fmaxf(rx, -1.0f), 1.0f);
    float dy = fminf(fmaxf(ry, -1.0f), 1.0f);
    float r  = sqrtf(dx * dx + dy * dy) * 2.0f - 1.0f;
    float th = atan2f(dy, dx) / 3.14159265358979323846f;
    float hr[4], ht[4];
    hat4(r, hr);
    hat4(th, ht);
    float* o = out + (size_t)e * 16;
#pragma unroll
    for (int a = 0; a < 4; ++a)
#pragma unroll
        for (int b = 0; b < 4; ++b)
            o[a * 4 + b] = hr[a] * ht[b];
}

// ---------------- CSR offsets from sorted target array ----------------
__global__ void offsets_kernel(const int* __restrict__ sorted, int E,
                               int* __restrict__ off, int N1) {
    int i = blockIdx.x * blockDim.x + threadIdx.x;
    if (i >= N1) return;
    int lo = 0, hi = E;
    while (lo < hi) {
        int mid = (lo + hi) >> 1;
        if (sorted[mid] < i) lo = mid + 1; else hi = mid;
    }
    off[i] = lo;
}

// ---------------- layer 1 (small Cin) ----------------
__global__ void layer1_kernel(const float* __restrict__ fluidFeats,
                              const float* __restrict__ boundaryFeats,
                              const float* __restrict__ fcW0, const float* __restrict__ fcb0,
                              const float* __restrict__ W0, const float* __restrict__ b0,
                              const float* __restrict__ W1, const float* __restrict__ b1,
                              const float* __restrict__ W2, const float* __restrict__ b2,
                              const float* __restrict__ W3, const float* __restrict__ b3,
                              const int* __restrict__ f_off, const int* __restrict__ fe_j,
                              const float* __restrict__ f_coeff,
                              const int* __restrict__ b_off, const int* __restrict__ be_b,
                              const float* __restrict__ b_coeff,
                              float* __restrict__ A1) {
    int n = blockIdx.x;
    int t = threadIdx.x;
    if (t >= 96) return;
    float val;
    if (t < 32) {
        val = fluidFeats[n * 2] * fcW0[t] + fluidFeats[n * 2 + 1] * fcW0[32 + t] + fcb0[t];
    } else if (t < 64) {
        int oc = t - 32;
        const float* W = (oc < 16) ? W0 : W1;
        int o16 = oc & 15;
        float s = (oc < 16) ? b0[o16] : b1[o16];
        int e1 = f_off[n + 1];
        for (int e = f_off[n]; e < e1; ++e) {
            const float* cf = f_coeff + (size_t)e * 16;
            int srcn = fe_j[e];
            float f0 = fluidFeats[srcn * 2], f1 = fluidFeats[srcn * 2 + 1];
            float acc = 0.0f;
#pragma unroll
            for (int k = 0; k < 16; ++k) {
                acc += cf[k] * (f0 * W[(k * 2 + 0) * 16 + o16] + f1 * W[(k * 2 + 1) * 16 + o16]);
            }
            s += acc;
        }
        val = s;
    } else {
        int oc = t - 64;
        const float* W = (oc < 16) ? W2 : W3;
        int o16 = oc & 15;
        float s = (oc < 16) ? b2[o16] : b3[o16];
        int e1 = b_off[n + 1];
        for (int e = b_off[n]; e < e1; ++e) {
            const float* cf = b_coeff + (size_t)e * 16;
            int srcn = be_b[e];
            float f0 = boundaryFeats[srcn * 3], f1 = boundaryFeats[srcn * 3 + 1],
                  f2 = boundaryFeats[srcn * 3 + 2];
            float acc = 0.0f;
#pragma unroll
            for (int k = 0; k < 16; ++k) {
                acc += cf[k] * (f0 * W[(k * 3 + 0) * 16 + o16] +
                                f1 * W[(k * 3 + 1) * 16 + o16] +
                                f2 * W[(k * 3 + 2) * 16 + o16]);
            }
            s += acc;
        }
        val = s;
    }
    A1[(size_t)n * 96 + t] = fmaxf(val, 0.0f);
}

// ---------------- layers 2/3: fused G-scatter + per-node GEMM ----------------
template <int CIN, bool RELU_IN, bool RESIDUAL, bool FINAL>
__global__ __launch_bounds__(256) void conv_layer_kernel(
    const float* __restrict__ X,
    const float* __restrict__ WA, const float* __restrict__ bA,
    const float* __restrict__ WB, const float* __restrict__ bB,
    const float* __restrict__ fcW, const float* __restrict__ fcb,
    const int* __restrict__ f_off, const int* __restrict__ fe_j,
    const float* __restrict__ f_coeff,
    float* __restrict__ OUT) {
    constexpr int NELEM = 16 * CIN;   // 1536 (L2) or 1024 (L3)
    constexpr int EPT = NELEM / 256;  // 6 or 4
    constexpr int BATCH = 8;
    constexpr int CHUNK = NELEM / 4;

    __shared__ float x_lds[CIN];
    __shared__ float feat[BATCH][CIN];
    __shared__ float co[BATCH][16];
    __shared__ float G[NELEM];
    __shared__ float red[4][64];

    int n = blockIdx.x;
    int t = threadIdx.x;

    for (int i = t; i < CIN; i += 256) {
        float v = X[(size_t)n * CIN + i];
        if (RELU_IN) v = fmaxf(v, 0.0f);
        x_lds[i] = v;
    }

    float acc[EPT];
    int kk[EPT], ii[EPT];
#pragma unroll
    for (int s = 0; s < EPT; ++s) {
        acc[s] = 0.0f;
        int j = s * 256 + t;
        kk[s] = j / CIN;
        ii[s] = j - kk[s] * CIN;
    }

    int e0 = f_off[n], e1 = f_off[n + 1];
    for (int eb = e0; eb < e1; eb += BATCH) {
        int cnt = min(BATCH, e1 - eb);
        __syncthreads();
        for (int idx = t; idx < cnt * 16; idx += 256) {
            int b = idx >> 4, c = idx & 15;
            co[b][c] = f_coeff[(size_t)(eb + b) * 16 + c];
        }
        for (int idx = t; idx < cnt * CIN; idx += 256) {
            int b = idx / CIN, i = idx - b * CIN;
            int srcn = fe_j[eb + b];
            float v = X[(size_t)srcn * CIN + i];
            if (RELU_IN) v = fmaxf(v, 0.0f);
            feat[b][i] = v;
        }
        __syncthreads();
#pragma unroll
        for (int b = 0; b < BATCH; ++b) {
            if (b >= cnt) break;
#pragma unroll
            for (int s = 0; s < EPT; ++s) acc[s] += co[b][kk[s]] * feat[b][ii[s]];
        }
    }
    __syncthreads();
#pragma unroll
    for (int s = 0; s < EPT; ++s) G[s * 256 + t] = acc[s];
    __syncthreads();

    int o = t & 63;
    int chunk = t >> 6;
    const float* Wp = (o < 32) ? WA : WB;
    int oc = o & 31;
    int j0 = chunk * CHUNK;
    float p0 = 0.f, p1 = 0.f, p2 = 0.f, p3 = 0.f;
    for (int j = j0; j < j0 + CHUNK; j += 4) {
        p0 += G[j + 0] * Wp[(size_t)(j + 0) * 32 + oc];
        p1 += G[j + 1] * Wp[(size_t)(j + 1) * 32 + oc];
        p2 += G[j + 2] * Wp[(size_t)(j + 2) * 32 + oc];
        p3 += G[j + 3] * Wp[(size_t)(j + 3) * 32 + oc];
    }
    red[chunk][o] = ((p0 + p1) + (p2 + p3));
    __syncthreads();
    if (t < 64) {
        float s = red[0][o] + red[1][o] + red[2][o] + red[3][o];
        s += (o < 32) ? bA[oc] : bB[oc];
        float fcv = fcb[o];
        for (int i = 0; i < CIN; ++i) fcv += x_lds[i] * fcW[i * 64 + o];
        s += fcv;
        if (RESIDUAL) s += X[(size_t)n * 64 + o];
        if (FINAL) s *= (1.0f / 128.0f);
        OUT[(size_t)n * 64 + o] = s;
    }
}

extern "C" void kernel_launch(void* const* d_in, const int* in_sizes, int n_in,
                              void* d_out, int out_size, void* d_ws, size_t ws_size,
                              hipStream_t stream) {
    const float* fluidPos      = (const float*)d_in[0];
    const float* boundaryPos   = (const float*)d_in[1];
    const float* fluidFeats    = (const float*)d_in[2];
    const float* boundaryFeats = (const float*)d_in[3];
    const int* fe_i = (const int*)d_in[4];
    const int* fe_j = (const int*)d_in[5];
    const int* be_f = (const int*)d_in[6];
    const int* be_b = (const int*)d_in[7];
    const float* W[8];
    const float* bb[8];
    for (int c = 0; c < 8; ++c) {
        W[c]  = (const float*)d_in[8 + 2 * c];
        bb[c] = (const float*)d_in[9 + 2 * c];
    }
    const float* fcW0 = (const float*)d_in[24];
    const float* fcb0 = (const float*)d_in[25];
    const float* fcW1 = (const float*)d_in[26];
    const float* fcb1 = (const float*)d_in[27];
    const float* fcW2 = (const float*)d_in[28];
    const float* fcb2 = (const float*)d_in[29];

    int NF = in_sizes[0] / 2;
    int EF = in_sizes[4];
    int EB = in_sizes[6];

    float* ws = (float*)d_ws;
    float* f_coeff = ws;                                  // EF*16
    float* b_coeff = f_coeff + (size_t)EF * 16;           // EB*16
    float* A1      = b_coeff + (size_t)EB * 16;           // NF*96
    float* ans2    = A1 + (size_t)NF * 96;                // NF*64
    int*   f_off   = (int*)(ans2 + (size_t)NF * 64);      // NF+1
    int*   b_off   = f_off + (NF + 1);                    // NF+1

    // fluid edges: d = -(P[fe_j] - P[fe_i]) / S  (NEG=true, A=P[fe_j], B=P[fe_i])
    coeff_kernel<true><<<(EF + 255) / 256, 256, 0, stream>>>(
        (const float2*)fluidPos, fe_j, (const float2*)fluidPos, fe_i, f_coeff, EF);
    // boundary edges: d = (bPos[be_b] - fPos[be_f]) / S
    coeff_kernel<false><<<(EB + 255) / 256, 256, 0, stream>>>(
        (const float2*)boundaryPos, be_b, (const float2*)fluidPos, be_f, b_coeff, EB);
    offsets_kernel<<<(NF + 1 + 255) / 256, 256, 0, stream>>>(fe_i, EF, f_off, NF + 1);
    offsets_kernel<<<(NF + 1 + 255) / 256, 256, 0, stream>>>(be_f, EB, b_off, NF + 1);

    layer1_kernel<<<NF, 128, 0, stream>>>(fluidFeats, boundaryFeats, fcW0, fcb0,
                                          W[0], bb[0], W[1], bb[1], W[2], bb[2], W[3], bb[3],
                                          f_off, fe_j, f_coeff, b_off, be_b, b_coeff, A1);

    conv_layer_kernel<96, false, false, false><<<NF, 256, 0, stream>>>(
        A1, W[4], bb[4], W[5], bb[5], fcW1, fcb1, f_off, fe_j, f_coeff, ans2);

    conv_layer_kernel<64, true, true, true><<<NF, 256, 0, stream>>>(
        ans2, W[6], bb[6], W[7], bb[7], fcW2, fcb2, f_off, fe_j, f_coeff, (float*)d_out);
}